// Round 7
// baseline (156.735 us; speedup 1.0000x reference)
//
#include <hip/hip_runtime.h>
#include <math.h>

// Maxwell IIR scan. stress[t] = a*stress[t-1] + E*(s[t]-s[t-1]), a=exp(-dt*E/eta),
// stress[0] = E*s[0] + eta*r[0].
//
// Reformulation: y[t]=stress[t]-E*s[t] => y[t]=a*y[t-1]+c*s[t-1], c=E*(a-1),
// so  stress[t] = E*s[t] + c*Z[t-1] + a^t*eta*r0,  Z = plain scan of s.
//
// R5:  coalesced float4 + DPP scan, 8192 one-shot waves: 41.1us.
// R7:  serial 4-chunk spans, 2048 waves: 50us (occupancy collapse).
// R8:  DPP bcast combine, WARM 512: 41.0us (chain not the gate).
// R9:  CHUNK 1024, 16384 waves: ~38.5us (backfill helped).
// R10: block LDS handoff, warm 32->8MB: ~37.9us. Traffic elasticity
//      ~0.03us/MB => NOT traffic-bound. ~3.7TB/s eff vs 6.4TB/s fills.
// R11: one-shot structure = load-latency CONVOY: every wave does
//      burst->stall->compute->die; __syncthreads drains vmcnt(0) at the
//      barrier (hipcc structural stall, guide §5). Fix = T3/T4 pattern:
//      two consecutive 2048-spans per block, ALL loads issued up front,
//      RAW s_barrier with lgkmcnt-only wait so span1 loads stay in
//      flight across barrier1 and land under span0 compute+stores.
//      Span1 state carried EXACTLY from span0 via LDS (barrier2); warm
//      stays 8MB (span0 only). 16384 waves, VGPR ~55 (8 waves/SIMD).
//      Predict kernel 37->30-33us; if unchanged -> fabric floor, stop.
// R12: resubmission of R11 unchanged — round 6 bench was an infra
//      failure (container acquire died twice, same as round 0; kernel
//      never ran). The R11 prediction and its roofline decision rule
//      stand.

#define DT_F  0.1f
#define S_LEN 65536
#define B_ROWS 256
#define CHUNK 512
#define WARM  512
#define WPB   4
#define SPAN  (CHUNK * WPB)        // 2048 elems per span
#define BSPAN (SPAN * 2)           // 4096 elems per block (2 spans)
#define BPR   (S_LEN / BSPAN)      // 16 blocks per row

typedef float nfloat4 __attribute__((ext_vector_type(4)));

template<int CTRL, int RM>
__device__ __forceinline__ float dpp0(float x) {
    // DPP with old=0: lanes with no valid source (or masked rows) get 0.
    return __int_as_float(__builtin_amdgcn_update_dpp(
        0, __float_as_int(x), CTRL, RM, 0xF, false));
}
template<int N>
__device__ __forceinline__ float dpp_shr(float x) { return dpp0<0x110 + N, 0xF>(x); }
__device__ __forceinline__ float bcast15(float x) { return dpp0<0x142, 0xA>(x); } // lane15->row1, lane47->row3
__device__ __forceinline__ float bcast31(float x) { return dpp0<0x143, 0xC>(x); } // lane31->rows2,3
__device__ __forceinline__ float wshr1(float x)   { return dpp0<0x138, 0xF>(x); } // whole-wave shift, lane0->0
__device__ __forceinline__ float rdl(float x, int l) {
    return __int_as_float(__builtin_amdgcn_readlane(__float_as_int(x), l));
}

// Raw workgroup barrier that does NOT drain vmcnt: LDS writes are made
// visible (lgkmcnt(0)), but in-flight global loads stay outstanding.
// Pattern per verified 8-phase template (m201) + rule #18 sched fences.
__device__ __forceinline__ void sync_lds_keep_vmem() {
    asm volatile("s_waitcnt lgkmcnt(0)" ::: "memory");
    __builtin_amdgcn_sched_barrier(0);
    __builtin_amdgcn_s_barrier();
    __builtin_amdgcn_sched_barrier(0);
    asm volatile("" ::: "memory");
}

__global__ __launch_bounds__(256) void maxwell_scan(
    const float* __restrict__ strain,
    const float* __restrict__ rate,
    const float* __restrict__ log_E,
    const float* __restrict__ log_eta,
    float* __restrict__ out)
{
    __shared__ float T0lds[WPB][2];   // span0 per-wave group totals
    __shared__ float T1lds[WPB][2];   // span1 per-wave group totals
    __shared__ float S0lds;           // span0 incoming state (warm or 0)
    __shared__ float Sendlds;         // span0 end state -> span1 incoming

    const int lane = threadIdx.x & 63;
    const int wv   = threadIdx.x >> 6;            // 0..3
    const int row  = blockIdx.x / BPR;
    const int off  = (blockIdx.x % BPR) * BSPAN;  // block's first elem in row

    const float E   = __expf(log_E[0]);
    const float eta = __expf(log_eta[0]);
    const float lam = -DT_F * E / eta;            // ln(a)
    const float a   = __expf(lam);
    const float a2 = a * a, a3 = a2 * a, a4 = a2 * a2, a8 = a4 * a4;
    const float a16 = a8 * a8, a32 = a16 * a16, a64 = a32 * a32;
    const float a256 = a64 * a64 * a64 * a64;
    const float a512 = a256 * a256;
    const float cc = E * (a - 1.0f);
    const float cca1 = cc * a, cca2 = cc * a2, cca3 = cc * a3;

    const float alane = __expf(lam * (float)(4 * lane));   // a^(4*lane)
    const float wX    = __expf(lam * (float)(4 * (lane & 15)));
    const float wm1   = wX * a4;                           // a^(4*(lrow+1))
    const float wm2   = (lane >= 48) ? wm1 * a64 : wm1;    // row3 jumps rows 0-1

    const int rowbase = row * S_LEN;
    const nfloat4* s4 = (const nfloat4*)(strain + rowbase);
    nfloat4*       o4 = (nfloat4*)(out + rowbase);

    // ---- ALL loads issued up front: warm (wv0), span0, span1 ----
    nfloat4 w0, w1;
    const bool do_warm = (wv == 0) && (off != 0);
    if (do_warm) {
        const int vw = ((off - WARM) >> 2) + lane;
        w0 = s4[vw]; w1 = s4[vw + 64];
    }
    const int vp0 = (off >> 2) + wv * (CHUNK / 4) + lane;  // span0 wave base
    const int vp1 = vp0 + (SPAN / 4);                      // span1 wave base
    nfloat4 p00 = s4[vp0], p01 = s4[vp0 + 64];
    nfloat4 p10 = s4[vp1], p11 = s4[vp1 + 64];

    float etar0 = 0.0f;
    if (off == 0) etar0 = eta * rate[rowbase];    // row-start blocks only

    // full-wave weighted inclusive scan of lane totals
    auto scanW = [&](float fl3) -> float {
        float D = fl3, v;
        v = dpp_shr<1>(D); D = fmaf(a4,  v, D);
        v = dpp_shr<2>(D); D = fmaf(a8,  v, D);
        v = dpp_shr<4>(D); D = fmaf(a16, v, D);
        v = dpp_shr<8>(D); D = fmaf(a32, v, D);
        v = bcast15(D);    D = fmaf(wm1, v, D);
        v = bcast31(D);    D = fmaf(wm2, v, D);
        return D;
    };
    auto groupW = [&](nfloat4 pf) -> float {
        float fl = pf.x;
        fl = fmaf(a, fl, pf.y); fl = fmaf(a, fl, pf.z); fl = fmaf(a, fl, pf.w);
        return scanW(fl);
    };

    // ---- phase 1a: span0 scans + warm; publish totals ----
    float W00 = groupW(p00), W01 = groupW(p01);
    if (lane == 63) { T0lds[wv][0] = W00; T0lds[wv][1] = W01; }
    if (wv == 0) {
        float S0 = 0.0f;
        if (off != 0) {
            float Tw0 = rdl(groupW(w0), 63);
            float Tw1 = rdl(groupW(w1), 63);
            S0 = fmaf(a256, Tw0, Tw1);            // warm scan of 512 elems
        }
        if (lane == 0) S0lds = S0;
    }
    sync_lds_keep_vmem();                         // barrier 1 (span1 loads live)

    // ---- phase 2 span0: exact chain, outputs ----
    float S = S0lds;
    for (int j = 0; j < wv; ++j) {
        float Tc = fmaf(a256, T0lds[j][0], T0lds[j][1]);
        S = fmaf(a512, S, Tc);
    }
    const float Sg0 = S;
    const float Sg1 = fmaf(a256, Sg0, T0lds[wv][0]);
    if (wv == WPB - 1) {
        float Send = fmaf(a256, Sg1, T0lds[WPB - 1][1]);
        if (lane == 0) Sendlds = Send;            // consumed after barrier 2
    }

    const float rl0 = etar0 * alane;              // eta*r0 * a^(4*lane)
    const float rl1 = rl0 * a, rl2 = rl0 * a2, rl3 = rl0 * a3;
    const float rb0 = __expf(lam * (float)(CHUNK * wv));   // a^(512*wv)

    auto outg = [&](nfloat4 pf, float W, float Sg, float bse, int vo) {
        float fl0 = pf.x;
        float fl1 = fmaf(a, fl0, pf.y);
        float fl2 = fmaf(a, fl1, pf.z);
        float X  = wshr1(W);                      // W[lane-1], lane0 -> 0
        float Xs = fmaf(alane, Sg, X);            // + incoming state
        nfloat4 o;
        o.x = fmaf(cc,   Xs, E * pf.x);
        o.y = fmaf(cca1, Xs, fmaf(cc, fl0, E * pf.y));
        o.z = fmaf(cca2, Xs, fmaf(cc, fl1, E * pf.z));
        o.w = fmaf(cca3, Xs, fmaf(cc, fl2, E * pf.w));
        o.x = fmaf(bse, rl0, o.x);
        o.y = fmaf(bse, rl1, o.y);
        o.z = fmaf(bse, rl2, o.z);
        o.w = fmaf(bse, rl3, o.w);
        o4[vo] = o;
    };
    outg(p00, W00, Sg0, rb0,        vp0);
    outg(p01, W01, Sg1, rb0 * a256, vp0 + 64);

    // ---- phase 1b: span1 scans (loads landed under span0 work) ----
    float W10 = groupW(p10), W11 = groupW(p11);
    if (lane == 63) { T1lds[wv][0] = W10; T1lds[wv][1] = W11; }
    sync_lds_keep_vmem();                         // barrier 2

    // ---- phase 2 span1: exact carried state, outputs ----
    float S2 = Sendlds;
    for (int j = 0; j < wv; ++j) {
        float Tc = fmaf(a256, T1lds[j][0], T1lds[j][1]);
        S2 = fmaf(a512, S2, Tc);
    }
    const float Sh0 = S2;
    const float Sh1 = fmaf(a256, Sh0, T1lds[wv][0]);
    // r0 term in span1: factor <= a^2048 ~ 1.3e-9 -> dropped (bse = 0)
    outg(p10, W10, Sh0, 0.0f, vp1);
    outg(p11, W11, Sh1, 0.0f, vp1 + 64);
}

extern "C" void kernel_launch(void* const* d_in, const int* in_sizes, int n_in,
                              void* d_out, int out_size, void* d_ws, size_t ws_size,
                              hipStream_t stream) {
    const float* strain  = (const float*)d_in[0];
    const float* rate    = (const float*)d_in[1];
    const float* log_E   = (const float*)d_in[2];
    const float* log_eta = (const float*)d_in[3];
    float* out = (float*)d_out;

    const int blocks = B_ROWS * BPR;              // 4096 blocks, 16384 waves
    maxwell_scan<<<blocks, 256, 0, stream>>>(strain, rate, log_E, log_eta, out);
}